// Round 4
// baseline (234.535 us; speedup 1.0000x reference)
//
#include <hip/hip_runtime.h>
#include <stdint.h>

// Problem constants (from reference setup_inputs)
#define NVARS   128
#define EMBED   256
#define L0      1024
#define NSTEPS  16
#define NBATCH  64
#define CHUNKS  32            // blocks per batch
#define RPC     32            // rows per chunk (L0 / CHUNKS)

typedef unsigned long long u64;
typedef unsigned int u32;

__device__ __forceinline__ u64 shfl_down_u64(u64 x, int off) {
    u32 lo = (u32)x, hi = (u32)(x >> 32);
    lo = __shfl_down(lo, off, 64);
    hi = __shfl_down(hi, off, 64);
    return ((u64)hi << 32) | (u64)lo;
}

// 2048 blocks x 256 threads. Block = (batch b, chunk) packs 32 rows:
// wave per row, lane l loads float4 (dims 4l..4l+3), 4 ballots, 4 u64/row to ws.
// Permuted bit layout (popcount/OR are permutation-invariant; output remaps):
//   word0 (A0)=lo32(m0)|lo32(m1)<<32  word1 (A1)=lo32(m2)|lo32(m3)<<32
//   word2 (B0)=hi32(m0)|hi32(m1)<<32  word3 (B1)=hi32(m2)|hi32(m3)<<32
//   var v: word = 2 + ((v>>1)&1), bit = (v>>2) | ((v&1)<<5)
// Last arriving block per batch (release/acquire via __threadfence + atomicAdd)
// runs the 16 autoregressive steps: thread t owns rows {t, 256+t, 512+t, 768+t}
// in registers; step 0 = full argmin reduction; steps 1..15 = incremental fast
// path (appended query rows have a==0 so cmin==0; their b-masks are subsets of
// the running union, so only base rows with current count 0 contribute).
__global__ __launch_bounds__(256) void fused_lastblock(const float4* __restrict__ tok4,
                                                       u64* __restrict__ packed,
                                                       u32* __restrict__ cnt,
                                                       float* __restrict__ out) {
    const int blk   = blockIdx.x;
    const int b     = blk >> 5;          // batch 0..63
    const int chunk = blk & 31;          // 0..31
    const int tid   = threadIdx.x;
    const int lane  = tid & 63;
    const int w     = tid >> 6;          // wave 0..3

    // ---- pack phase: 8 rows per wave, all loads in flight ----
    const int row0 = chunk * RPC + w * 8;                   // within batch
    const float4* base = tok4 + ((size_t)b * L0 + row0) * 64;
    float4 v[8];
    #pragma unroll
    for (int r = 0; r < 8; ++r) v[r] = base[(size_t)r * 64 + lane];
    #pragma unroll
    for (int r = 0; r < 8; ++r) {
        u64 m0 = __ballot(v[r].x > 0.5f);
        u64 m1 = __ballot(v[r].y > 0.5f);
        u64 m2 = __ballot(v[r].z > 0.5f);
        u64 m3 = __ballot(v[r].w > 0.5f);
        u64 wd;
        if      (lane == 0) wd = (m0 & 0xffffffffull) | (m1 << 32);
        else if (lane == 1) wd = (m2 & 0xffffffffull) | (m3 << 32);
        else if (lane == 2) wd = (m0 >> 32) | (m1 & 0xffffffff00000000ull);
        else                wd = (m2 >> 32) | (m3 & 0xffffffff00000000ull);
        if (lane < 4) packed[((size_t)b * L0 + row0 + r) * 4 + lane] = wd;
    }

    // ---- arrival: device-scope release, count, last block proceeds ----
    __threadfence();                     // release this block's packed stores
    __syncthreads();
    __shared__ u32 s_old;
    if (tid == 0) s_old = atomicAdd(&cnt[b], 1u);
    __syncthreads();
    if (s_old != CHUNKS - 1) return;     // not last: done
    __threadfence();                     // acquire all blocks' packed stores

    // ---- steps phase (only 64 blocks reach here, one per batch) ----
    __shared__ int s_c[4];
    __shared__ u64 s_o0[4], s_o1[4];
    __shared__ u64 s_rp0, s_rp1;         // pure r_0 (step 0 has 3-way output)
    __shared__ u32 s_acc[4];             // running union: qb_s growing to r_s
    __shared__ u64 s_qb0s, s_qb1s;

    u64 ra0[4], ra1[4], rb0[4], rb1[4];
    const u64* p = packed + (size_t)b * L0 * 4;
    #pragma unroll
    for (int i = 0; i < 4; ++i) {
        const u64* q = p + (size_t)(i * 256 + tid) * 4;
        ra0[i] = q[0]; ra1[i] = q[1]; rb0[i] = q[2]; rb1[i] = q[3];
    }
    if (tid == 255) { s_qb0s = rb0[3]; s_qb1s = rb1[3]; }   // row 1023 = query_0
    __syncthreads();
    const u64 qb0 = s_qb0s, qb1 = s_qb1s;

    // step 0: full min + argmin-OR reduction
    int c[4];
    int cm = 0x7fffffff; u64 o0 = 0, o1 = 0;
    #pragma unroll
    for (int i = 0; i < 4; ++i) {
        c[i] = __popcll(ra0[i] & ~qb0) + __popcll(ra1[i] & ~qb1);
        if (c[i] < cm)       { cm = c[i]; o0 = rb0[i]; o1 = rb1[i]; }
        else if (c[i] == cm) { o0 |= rb0[i]; o1 |= rb1[i]; }
    }
    #pragma unroll
    for (int off = 32; off; off >>= 1) {
        int c2 = __shfl_down(cm, off, 64);
        u64 p0 = shfl_down_u64(o0, off), p1 = shfl_down_u64(o1, off);
        if (c2 < cm)       { cm = c2; o0 = p0; o1 = p1; }
        else if (c2 == cm) { o0 |= p0; o1 |= p1; }
    }
    if (lane == 0) { s_c[w] = cm; s_o0[w] = o0; s_o1[w] = o1; }
    __syncthreads();
    if (tid == 0) {
        int rc = s_c[0]; u64 r0 = s_o0[0], r1 = s_o1[0];
        #pragma unroll
        for (int k = 1; k < 4; ++k) {
            if (s_c[k] < rc)       { rc = s_c[k]; r0 = s_o0[k]; r1 = s_o1[k]; }
            else if (s_c[k] == rc) { r0 |= s_o0[k]; r1 |= s_o1[k]; }
        }
        s_rp0 = r0; s_rp1 = r1;
        u64 u0 = r0 | qb0, u1 = r1 | qb1;   // qb_1
        s_acc[0] = (u32)u0; s_acc[1] = (u32)(u0 >> 32);
        s_acc[2] = (u32)u1; s_acc[3] = (u32)(u1 >> 32);
    }
    __syncthreads();

    const float TP = 0.46211715726000974f;   // tanh(0.5)
    float* ob = out + (size_t)b * NSTEPS * NVARS;
    if (tid < NVARS) {
        const int wi = (tid >> 1) & 1, bit = (tid >> 2) | ((tid & 1) << 5);
        u64 rw = wi ? s_rp1 : s_rp0;
        u64 qw = wi ? qb1 : qb0;
        ob[tid] = ((rw >> bit) & 1) ? 1.0f : (((qw >> bit) & 1) ? TP : -TP);
    }
    u64 rcur0 = (u64)s_acc[0] | ((u64)s_acc[1] << 32);   // qb_1
    u64 rcur1 = (u64)s_acc[2] | ((u64)s_acc[3] << 32);
    u64 qbp0 = qb0, qbp1 = qb1;
    __syncthreads();   // reads of s_rp/s_acc done before step-1 atomics

    // steps 1..15: incremental fast path (cmin == 0 guaranteed)
    for (int s = 1; s < NSTEPS; ++s) {
        const u64 d0 = rcur0 & ~qbp0, d1 = rcur1 & ~qbp1;   // qb delta (uniform)
        if (d0 | d1) {
            #pragma unroll
            for (int i = 0; i < 4; ++i)
                c[i] -= __popcll(ra0[i] & d0) + __popcll(ra1[i] & d1);
            qbp0 = rcur0; qbp1 = rcur1;
        }
        #pragma unroll
        for (int i = 0; i < 4; ++i) {
            if (c[i] == 0) {   // argmin base row: contribute its new b-bits
                u64 nb0 = rb0[i] & ~rcur0, nb1 = rb1[i] & ~rcur1;
                if (nb0 | nb1) {
                    if ((u32)nb0)         atomicOr(&s_acc[0], (u32)nb0);
                    if ((u32)(nb0 >> 32)) atomicOr(&s_acc[1], (u32)(nb0 >> 32));
                    if ((u32)nb1)         atomicOr(&s_acc[2], (u32)nb1);
                    if ((u32)(nb1 >> 32)) atomicOr(&s_acc[3], (u32)(nb1 >> 32));
                }
            }
        }
        __syncthreads();   // atomics complete
        const u64 rn0 = (u64)s_acc[0] | ((u64)s_acc[1] << 32);   // r_s
        const u64 rn1 = (u64)s_acc[2] | ((u64)s_acc[3] << 32);
        if (tid < NVARS) {
            const int wi = (tid >> 1) & 1, bit = (tid >> 2) | ((tid & 1) << 5);
            u64 rw = wi ? rn1 : rn0;
            // r_s >= qb_s: qb-bit set => r-bit set => 1.0; else qb-bit is 0 => -TP
            ob[s * NVARS + tid] = ((rw >> bit) & 1) ? 1.0f : -TP;
        }
        rcur0 = rn0; rcur1 = rn1;
        __syncthreads();   // reads done before next step's atomics
    }
}

extern "C" void kernel_launch(void* const* d_in, const int* in_sizes, int n_in,
                              void* d_out, int out_size, void* d_ws, size_t ws_size,
                              hipStream_t stream) {
    const float4* tok4 = (const float4*)d_in[0];
    float* out = (float*)d_out;
    u64* packed = (u64*)d_ws;                                  // 2 MiB
    u32* cnt = (u32*)((char*)d_ws + (size_t)NBATCH * L0 * 4 * sizeof(u64));

    hipMemsetAsync(cnt, 0, NBATCH * sizeof(u32), stream);      // arrival counters
    fused_lastblock<<<NBATCH * CHUNKS, 256, 0, stream>>>(tok4, packed, cnt, out);
}

// Round 5
// 27.966 us; speedup vs baseline: 8.3864x; 8.3864x over previous
//
#include <hip/hip_runtime.h>
#include <stdint.h>

// Problem constants (from reference setup_inputs)
#define NVARS   128
#define EMBED   256
#define L0      1024
#define NSTEPS  16
#define NBATCH  64

typedef unsigned long long u64;
typedef unsigned int u32;

__device__ __forceinline__ u64 shfl_down_u64(u64 x, int off) {
    u32 lo = (u32)x, hi = (u32)(x >> 32);
    lo = __shfl_down(lo, off, 64);
    hi = __shfl_down(hi, off, 64);
    return ((u64)hi << 32) | (u64)lo;
}

// Pack tokens [65536 rows][256 fp32 {0,1}] -> 4 u64 words/row in ws.
// 2048 blocks x 256 threads; wave handles 8 CONSECUTIVE rows (8 KB contiguous
// span); lane l loads float4 = dims 4l..4l+3; loads batched before ballots.
// Permuted bit layout (popcount/OR are permutation-invariant; output remaps):
//   word0 (A0)=lo32(m0)|lo32(m1)<<32  word1 (A1)=lo32(m2)|lo32(m3)<<32
//   word2 (B0)=hi32(m0)|hi32(m1)<<32  word3 (B1)=hi32(m2)|hi32(m3)<<32
//   var v (0..127): word = 2 + ((v>>1)&1), bit = (v>>2) | ((v&1)<<5)
__global__ __launch_bounds__(256) void pack_kernel(const float4* __restrict__ tok4,
                                                   u64* __restrict__ packed) {
    const int lane = threadIdx.x & 63;
    const int gw   = (blockIdx.x * 256 + threadIdx.x) >> 6;   // 0..8191
    const int row0 = gw * 8;
    const float4* base = tok4 + (size_t)row0 * 64;

    float4 v[8];
    #pragma unroll
    for (int r = 0; r < 8; ++r) v[r] = base[(size_t)r * 64 + lane];

    #pragma unroll
    for (int r = 0; r < 8; ++r) {
        u64 m0 = __ballot(v[r].x > 0.5f);
        u64 m1 = __ballot(v[r].y > 0.5f);
        u64 m2 = __ballot(v[r].z > 0.5f);
        u64 m3 = __ballot(v[r].w > 0.5f);
        u64 wd;
        if      (lane == 0) wd = (m0 & 0xffffffffull) | (m1 << 32);
        else if (lane == 1) wd = (m2 & 0xffffffffull) | (m3 << 32);
        else if (lane == 2) wd = (m0 >> 32) | (m1 & 0xffffffff00000000ull);
        else                wd = (m2 >> 32) | (m3 & 0xffffffff00000000ull);
        if (lane < 4) packed[(size_t)(row0 + r) * 4 + lane] = wd;
    }
}

// One block per batch item (64 blocks x 1024 threads), thread t owns row t.
// Step 0: full min + argmin-OR reduction.
// Steps 1..15: incremental fast path — appended query rows have a==0 so
// cmin==0 always; their b-masks are subsets of the running union; counts
// updated by popcount(a & delta_qb); base rows with count 0 OR their b-bits in.
__global__ __launch_bounds__(1024) void steps_kernel(const u64* __restrict__ packed,
                                                     float* __restrict__ out) {
    __shared__ int s_c[16];
    __shared__ u64 s_o0[16], s_o1[16];
    __shared__ u64 s_rp0, s_rp1;         // pure r_0 (step 0 has 3-way output)
    __shared__ u32 s_acc[4];             // running union: qb_s growing to r_s
    __shared__ u64 s_qb0s, s_qb1s;

    const int b    = blockIdx.x;
    const int tid  = threadIdx.x;
    const int lane = tid & 63;
    const int w    = tid >> 6;           // wave 0..15

    const u64* q = packed + ((size_t)b * L0 + tid) * 4;
    const u64 ra0 = q[0], ra1 = q[1], rb0 = q[2], rb1 = q[3];
    if (tid == L0 - 1) { s_qb0s = rb0; s_qb1s = rb1; }   // row 1023 = query_0
    __syncthreads();
    const u64 qb0 = s_qb0s, qb1 = s_qb1s;

    // ---- step 0: full min + argmin-OR reduction ----
    int c = __popcll(ra0 & ~qb0) + __popcll(ra1 & ~qb1);
    int cm = c; u64 o0 = rb0, o1 = rb1;
    #pragma unroll
    for (int off = 32; off; off >>= 1) {
        int c2 = __shfl_down(cm, off, 64);
        u64 p0 = shfl_down_u64(o0, off), p1 = shfl_down_u64(o1, off);
        if (c2 < cm)       { cm = c2; o0 = p0; o1 = p1; }
        else if (c2 == cm) { o0 |= p0; o1 |= p1; }
    }
    if (lane == 0) { s_c[w] = cm; s_o0[w] = o0; s_o1[w] = o1; }
    __syncthreads();
    if (tid == 0) {
        int rc = s_c[0]; u64 r0 = s_o0[0], r1 = s_o1[0];
        #pragma unroll
        for (int k = 1; k < 16; ++k) {
            if (s_c[k] < rc)       { rc = s_c[k]; r0 = s_o0[k]; r1 = s_o1[k]; }
            else if (s_c[k] == rc) { r0 |= s_o0[k]; r1 |= s_o1[k]; }
        }
        s_rp0 = r0; s_rp1 = r1;
        u64 u0 = r0 | qb0, u1 = r1 | qb1;   // qb_1
        s_acc[0] = (u32)u0; s_acc[1] = (u32)(u0 >> 32);
        s_acc[2] = (u32)u1; s_acc[3] = (u32)(u1 >> 32);
    }
    __syncthreads();

    const float TP = 0.46211715726000974f;   // tanh(0.5)
    float* ob = out + (size_t)b * NSTEPS * NVARS;
    if (tid < NVARS) {
        const int wi = (tid >> 1) & 1, bit = (tid >> 2) | ((tid & 1) << 5);
        u64 rw = wi ? s_rp1 : s_rp0;
        u64 qw = wi ? qb1 : qb0;
        ob[tid] = ((rw >> bit) & 1) ? 1.0f : (((qw >> bit) & 1) ? TP : -TP);
    }
    u64 rcur0 = (u64)s_acc[0] | ((u64)s_acc[1] << 32);   // qb_1
    u64 rcur1 = (u64)s_acc[2] | ((u64)s_acc[3] << 32);
    u64 qbp0 = qb0, qbp1 = qb1;
    int cc = c;                                           // count vs qbp
    __syncthreads();   // reads of s_rp/s_acc done before step-1 atomics

    // ---- steps 1..15: incremental fast path (cmin == 0 guaranteed) ----
    for (int s = 1; s < NSTEPS; ++s) {
        const u64 d0 = rcur0 & ~qbp0, d1 = rcur1 & ~qbp1;   // qb delta (uniform)
        if (d0 | d1) {
            cc -= __popcll(ra0 & d0) + __popcll(ra1 & d1);
            qbp0 = rcur0; qbp1 = rcur1;
        }
        if (cc == 0) {   // argmin base row: contribute its new b-bits
            u64 nb0 = rb0 & ~rcur0, nb1 = rb1 & ~rcur1;
            if ((u32)nb0)         atomicOr(&s_acc[0], (u32)nb0);
            if ((u32)(nb0 >> 32)) atomicOr(&s_acc[1], (u32)(nb0 >> 32));
            if ((u32)nb1)         atomicOr(&s_acc[2], (u32)nb1);
            if ((u32)(nb1 >> 32)) atomicOr(&s_acc[3], (u32)(nb1 >> 32));
        }
        __syncthreads();   // atomics complete
        const u64 rn0 = (u64)s_acc[0] | ((u64)s_acc[1] << 32);   // r_s
        const u64 rn1 = (u64)s_acc[2] | ((u64)s_acc[3] << 32);
        if (tid < NVARS) {
            const int wi = (tid >> 1) & 1, bit = (tid >> 2) | ((tid & 1) << 5);
            u64 rw = wi ? rn1 : rn0;
            // r_s >= qb_s: qb-bit set => r-bit set => 1.0; else qb-bit is 0 => -TP
            ob[s * NVARS + tid] = ((rw >> bit) & 1) ? 1.0f : -TP;
        }
        rcur0 = rn0; rcur1 = rn1;
        __syncthreads();   // reads done before next step's atomics
    }
}

extern "C" void kernel_launch(void* const* d_in, const int* in_sizes, int n_in,
                              void* d_out, int out_size, void* d_ws, size_t ws_size,
                              hipStream_t stream) {
    const float4* tok4 = (const float4*)d_in[0];
    float* out = (float*)d_out;
    u64* packed = (u64*)d_ws;   // 2 MiB of the 256 MiB workspace

    pack_kernel<<<2048, 256, 0, stream>>>(tok4, packed);
    steps_kernel<<<NBATCH, 1024, 0, stream>>>(packed, out);
}

// Round 6
// 22.092 us; speedup vs baseline: 10.6162x; 1.2659x over previous
//
#include <hip/hip_runtime.h>
#include <stdint.h>

// Problem constants (from reference setup_inputs)
#define NVARS   128
#define EMBED   256
#define L0      1024
#define NSTEPS  16
#define NBATCH  64

typedef unsigned long long u64;
typedef unsigned int u32;

__device__ __forceinline__ u64 shfl_xor_u64(u64 x, int m) {
    u32 lo = (u32)x, hi = (u32)(x >> 32);
    lo = __shfl_xor(lo, m, 64);
    hi = __shfl_xor(hi, m, 64);
    return ((u64)hi << 32) | (u64)lo;
}
__device__ __forceinline__ u64 shfl_u64(u64 x, int src) {
    u32 lo = (u32)x, hi = (u32)(x >> 32);
    lo = __shfl(lo, src, 64);
    hi = __shfl(hi, src, 64);
    return ((u64)hi << 32) | (u64)lo;
}

// Pack tokens [65536 rows][256 fp32 {0,1}] -> 4 u64 words/row in ws.
// 4096 blocks x 256 threads (16384 waves = 4 waves/SIMD for latency hiding);
// wave handles 4 consecutive rows; lane l loads float4 = dims 4l..4l+3;
// all 4 loads issued before any ballot.
// Permuted bit layout (popcount/OR are permutation-invariant; output remaps):
//   word0 (A0)=lo32(m0)|lo32(m1)<<32  word1 (A1)=lo32(m2)|lo32(m3)<<32
//   word2 (B0)=hi32(m0)|hi32(m1)<<32  word3 (B1)=hi32(m2)|hi32(m3)<<32
//   var v (0..127): word = 2 + ((v>>1)&1), bit = (v>>2) | ((v&1)<<5)
__global__ __launch_bounds__(256) void pack_kernel(const float4* __restrict__ tok4,
                                                   u64* __restrict__ packed) {
    const int lane = threadIdx.x & 63;
    const int gw   = (blockIdx.x * 256 + threadIdx.x) >> 6;   // 0..16383
    const int row0 = gw * 4;
    const float4* base = tok4 + (size_t)row0 * 64;

    float4 v[4];
    #pragma unroll
    for (int r = 0; r < 4; ++r) v[r] = base[(size_t)r * 64 + lane];

    #pragma unroll
    for (int r = 0; r < 4; ++r) {
        u64 m0 = __ballot(v[r].x > 0.5f);
        u64 m1 = __ballot(v[r].y > 0.5f);
        u64 m2 = __ballot(v[r].z > 0.5f);
        u64 m3 = __ballot(v[r].w > 0.5f);
        u64 wd;
        if      (lane == 0) wd = (m0 & 0xffffffffull) | (m1 << 32);
        else if (lane == 1) wd = (m2 & 0xffffffffull) | (m3 << 32);
        else if (lane == 2) wd = (m0 >> 32) | (m1 & 0xffffffff00000000ull);
        else                wd = (m2 >> 32) | (m3 & 0xffffffff00000000ull);
        if (lane < 4) packed[(size_t)(row0 + r) * 4 + lane] = wd;
    }
}

// ONE WAVE per batch item (64 blocks x 64 threads): zero barriers, zero LDS.
// Lane owns 16 rows (i*64+lane) in registers (~128 VGPR).
// Step 0: full min + tie-OR reduction via 6-stage shfl_xor butterfly (the merge
//   is a semilattice op, so every lane ends with the exact full reduction).
// Steps 1..15: incremental fast path — appended query rows have a==0 so cmin==0
//   always and their b-masks are subsets of the running union; counts updated
//   exactly by popcount(a & delta); rows at count 0 OR their b-bits in.
// Fixpoint early-out: if the union stops growing, counts can never change again
//   -> all remaining steps produce identical output; fill and return.
__global__ __launch_bounds__(64) void steps_kernel(const u64* __restrict__ packed,
                                                   float* __restrict__ out) {
    const int b    = blockIdx.x;
    const int lane = threadIdx.x;          // 0..63

    u64 ra0[16], ra1[16], rb0[16], rb1[16];
    const u64* p = packed + (size_t)b * L0 * 4;
    #pragma unroll
    for (int i = 0; i < 16; ++i) {
        const u64* q = p + (size_t)(i * 64 + lane) * 4;
        ra0[i] = q[0]; ra1[i] = q[1]; rb0[i] = q[2]; rb1[i] = q[3];
    }
    // query_0 = b-half of row 1023 (i=15, lane 63)
    const u64 qb0 = shfl_u64(rb0[15], 63);
    const u64 qb1 = shfl_u64(rb1[15], 63);

    // ---- step 0: counts + full min/tie-OR butterfly ----
    int cc[16];
    int cm = 0x7fffffff; u64 o0 = 0, o1 = 0;
    #pragma unroll
    for (int i = 0; i < 16; ++i) {
        cc[i] = __popcll(ra0[i] & ~qb0) + __popcll(ra1[i] & ~qb1);
        if (cc[i] < cm)       { cm = cc[i]; o0 = rb0[i]; o1 = rb1[i]; }
        else if (cc[i] == cm) { o0 |= rb0[i]; o1 |= rb1[i]; }
    }
    #pragma unroll
    for (int m = 1; m < 64; m <<= 1) {
        int c2 = __shfl_xor(cm, m, 64);
        u64 p0 = shfl_xor_u64(o0, m), p1 = shfl_xor_u64(o1, m);
        if (c2 < cm)       { cm = c2; o0 = p0; o1 = p1; }
        else if (c2 == cm) { o0 |= p0; o1 |= p1; }
    }
    // every lane now holds the exact (cm, o0, o1)

    const float TP = 0.46211715726000974f;   // tanh(0.5)
    float* ob = out + (size_t)b * NSTEPS * NVARS;

    // step-0 output (3-way: 1.0 / +TP / -TP based on pure r_0 and qb)
    {
        const int v1 = lane, v2 = lane + 64;
        const int wi1 = (v1 >> 1) & 1, bit1 = (v1 >> 2) | ((v1 & 1) << 5);
        const int wi2 = (v2 >> 1) & 1, bit2 = (v2 >> 2) | ((v2 & 1) << 5);
        u64 rw1 = wi1 ? o1 : o0, qw1 = wi1 ? qb1 : qb0;
        u64 rw2 = wi2 ? o1 : o0, qw2 = wi2 ? qb1 : qb0;
        ob[v1] = ((rw1 >> bit1) & 1) ? 1.0f : (((qw1 >> bit1) & 1) ? TP : -TP);
        ob[v2] = ((rw2 >> bit2) & 1) ? 1.0f : (((qw2 >> bit2) & 1) ? TP : -TP);
    }

    u64 rcur0 = o0 | qb0, rcur1 = o1 | qb1;   // qb_1 (running union)
    u64 qbp0 = qb0, qbp1 = qb1;               // counts currently vs qbp

    // ---- steps 1..15 ----
    for (int s = 1; s < NSTEPS; ++s) {
        const u64 d0 = rcur0 & ~qbp0, d1 = rcur1 & ~qbp1;   // uniform across lanes
        if (d0 | d1) {
            #pragma unroll
            for (int i = 0; i < 16; ++i)
                cc[i] -= __popcll(ra0[i] & d0) + __popcll(ra1[i] & d1);
            qbp0 = rcur0; qbp1 = rcur1;
        }
        u64 nb0 = 0, nb1 = 0;
        #pragma unroll
        for (int i = 0; i < 16; ++i)
            if (cc[i] == 0) { nb0 |= rb0[i]; nb1 |= rb1[i]; }
        nb0 &= ~rcur0; nb1 &= ~rcur1;

        if (__ballot((nb0 | nb1) != 0ull)) {
            // union grows: OR-butterfly (all lanes get full union delta)
            #pragma unroll
            for (int m = 1; m < 64; m <<= 1) {
                nb0 |= shfl_xor_u64(nb0, m);
                nb1 |= shfl_xor_u64(nb1, m);
            }
            rcur0 |= nb0; rcur1 |= nb1;
            const int v1 = lane, v2 = lane + 64;
            const int wi1 = (v1 >> 1) & 1, bit1 = (v1 >> 2) | ((v1 & 1) << 5);
            const int wi2 = (v2 >> 1) & 1, bit2 = (v2 >> 2) | ((v2 & 1) << 5);
            u64 rw1 = wi1 ? rcur1 : rcur0;
            u64 rw2 = wi2 ? rcur1 : rcur0;
            // r_s >= qb_s: qb-bit set => r-bit set => 1.0; else qb-bit 0 => -TP
            ob[s * NVARS + v1] = ((rw1 >> bit1) & 1) ? 1.0f : -TP;
            ob[s * NVARS + v2] = ((rw2 >> bit2) & 1) ? 1.0f : -TP;
        } else {
            // fixpoint: union stable forever -> all remaining steps identical
            const int v1 = lane, v2 = lane + 64;
            const int wi1 = (v1 >> 1) & 1, bit1 = (v1 >> 2) | ((v1 & 1) << 5);
            const int wi2 = (v2 >> 1) & 1, bit2 = (v2 >> 2) | ((v2 & 1) << 5);
            u64 rw1 = wi1 ? rcur1 : rcur0;
            u64 rw2 = wi2 ? rcur1 : rcur0;
            float f1 = ((rw1 >> bit1) & 1) ? 1.0f : -TP;
            float f2 = ((rw2 >> bit2) & 1) ? 1.0f : -TP;
            for (int t = s; t < NSTEPS; ++t) {
                ob[t * NVARS + v1] = f1;
                ob[t * NVARS + v2] = f2;
            }
            return;
        }
    }
}

extern "C" void kernel_launch(void* const* d_in, const int* in_sizes, int n_in,
                              void* d_out, int out_size, void* d_ws, size_t ws_size,
                              hipStream_t stream) {
    const float4* tok4 = (const float4*)d_in[0];
    float* out = (float*)d_out;
    u64* packed = (u64*)d_ws;   // 2 MiB of the workspace

    pack_kernel<<<4096, 256, 0, stream>>>(tok4, packed);
    steps_kernel<<<NBATCH, 64, 0, stream>>>(packed, out);
}